// Round 11
// baseline (197.562 us; speedup 1.0000x reference)
//
#include <hip/hip_runtime.h>
#include <math.h>

#define B_SZ   4
#define N_PTS  2048
#define EPSF   1e-6f
#define CAP    768     // candidate-list capacity per (wave,target)

// ---- workspace float-index layout ----
#define WS_KNN_R 0                       // 4*6144 real knn dists
#define WS_KNN_F 24576                   // 4*6144 fake knn dists
#define WS_FEAS  49152                   // 1024 feasibility partials
#define WS_PSIP  50176                   // 1024 psi partials
#define WS_RSUM  51200                   // 4 per-batch sum|r|
#define WS_Q     51204                   // 58 quantile outputs
#define WS_TICKC 51264                   // 8 per-cloud tickets (uint)
#define WS_TICK2 51272                   // global quant ticket (uint)
#define QZF (WS_Q + 0)
#define QZR (WS_Q + 7)
#define QXF (WS_Q + 14)
#define QXR (WS_Q + 19)
#define QYF (WS_Q + 24)
#define QYR (WS_Q + 29)
#define QDR (WS_Q + 34)   // 4 batches x 3 (real knn)
#define QDF (WS_Q + 46)   // 4 batches x 3 (fake knn)
#define COMP_SCALE 128.0f     // 2048 bins over [-8,8), width 1/128
#define KNN_SCALE  512.0f     // 2048 bins over [0,4),  width 1/512

__constant__ float c_qs7[7] = {0.05f, 0.1f, 0.25f, 0.5f, 0.75f, 0.9f, 0.95f};
__constant__ float c_qs5[5] = {0.05f, 0.25f, 0.5f, 0.75f, 0.95f};
__constant__ float c_qs3[3] = {0.05f, 0.5f, 0.95f};

#define CE(a, b) { float _lo = fminf(a, b), _hi = fmaxf(a, b); a = _lo; b = _hi; }

__device__ __forceinline__ void ins3a(float m[3], float v) {
    float h0 = fmaxf(m[0], v); m[0] = fminf(m[0], v);
    float h1 = fmaxf(m[1], h0); m[1] = fminf(m[1], h0);
    m[2] = fminf(m[2], h1);
}
__device__ __forceinline__ void ins5a(float m[5], float v) {
    float h0 = fmaxf(m[0], v); m[0] = fminf(m[0], v);
    float h1 = fmaxf(m[1], h0); m[1] = fminf(m[1], h0);
    float h2 = fmaxf(m[2], h1); m[2] = fminf(m[2], h1);
    float h3 = fmaxf(m[3], h2); m[3] = fminf(m[3], h2);
    m[4] = fminf(m[4], h3);
}

// shared memory union: pair phase vs quant/final phase
union SmemU {
    struct {
        float2 sxy[N_PTS];                // 16 KB
        float  sr[N_PTS];                 // 8 KB
        float  red[256];                  // 1 KB
        unsigned short slist[4 * 2 * CAP];// 12 KB
    } p1;                                 // 37888 B
    struct {
        unsigned int hist[4][2048];       // 32 KB (hist[0] reused as cum)
        unsigned int swsum[4];
        float sred[256];
        int slast;
    } p2;                                 // ~33.8 KB
};

// block-wide 2048-bin histogram quantiles (all 256 threads participate)
__device__ __forceinline__ void quant_hist(SmemU& sm,
                                           const float* __restrict__ src, int step, int n,
                                           float bias, float scale,
                                           const float* qs, int nq,
                                           float vlo, float vw,
                                           float* __restrict__ ws, int slot,
                                           int tid, int wave, int lane) {
    unsigned int* hflat = &sm.p2.hist[0][0];
#pragma unroll
    for (int i = 0; i < 32; ++i) hflat[i * 256 + tid] = 0u;
    __syncthreads();
    for (int e = tid; e < n; e += 256) {
        const float v = src[(size_t)e * step];
        int bin = (int)floorf((v + bias) * scale);
        bin = (bin < 0) ? 0 : (bin > 2047 ? 2047 : bin);
        atomicAdd(&sm.p2.hist[wave][bin], 1u);
    }
    __syncthreads();
    unsigned int c[8], ps = 0;
    const int base = tid * 8;
#pragma unroll
    for (int i = 0; i < 8; ++i) {
        c[i] = sm.p2.hist[0][base + i] + sm.p2.hist[1][base + i]
             + sm.p2.hist[2][base + i] + sm.p2.hist[3][base + i];
        ps += c[i];
    }
    unsigned int incl = ps;
#pragma unroll
    for (int off = 1; off < 64; off <<= 1) {
        unsigned int nb = (unsigned int)__shfl_up((int)incl, off);
        if (lane >= off) incl += nb;
    }
    if (lane == 63) sm.p2.swsum[wave] = incl;
    __syncthreads();
    unsigned int woff = 0;
    for (int w2 = 0; w2 < wave; ++w2) woff += sm.p2.swsum[w2];
    unsigned int run = incl - ps + woff;
#pragma unroll
    for (int i = 0; i < 8; ++i) { run += c[i]; hflat[base + i] = run; }
    __syncthreads();
    if (tid < nq) {
        const float pos = qs[tid] * (float)(n - 1);
        const int k = (int)pos;
        const float frac = pos - (float)k;
        float v2[2];
#pragma unroll
        for (int t = 0; t < 2; ++t) {
            const unsigned int r = (unsigned int)(k + t);
            int lo_ = 0, hi_ = 2047;
            while (lo_ < hi_) {
                const int mid = (lo_ + hi_) >> 1;
                if (hflat[mid] > r) hi_ = mid; else lo_ = mid + 1;
            }
            const unsigned int excl = (lo_ > 0) ? hflat[lo_ - 1] : 0u;
            const unsigned int cnt  = hflat[lo_] - excl;
            v2[t] = vlo + ((float)lo_ + ((float)(r - excl) + 0.5f) / (float)cnt) * vw;
        }
        ws[slot + tid] = v2[0] + frac * (v2[1] - v2[0]);
    }
    __syncthreads();
}

// final combine (runs in the last ticket-2 block)
__device__ __forceinline__ void final_combine(SmemU& sm,
                                              const float* __restrict__ fouts,
                                              float* __restrict__ ws,
                                              float* __restrict__ out, int tid) {
    float fs = 0.f, ps2 = 0.f;
    for (int t = tid; t < 1024; t += 256) {
        fs  += ws[WS_FEAS + t];
        ps2 += ws[WS_PSIP + t];
    }
    sm.p2.sred[tid] = fs;
    __syncthreads();
    for (int s = 128; s > 0; s >>= 1) {
        if (tid < s) sm.p2.sred[tid] += sm.p2.sred[tid + s];
        __syncthreads();
    }
    const float s_feas = sm.p2.sred[0];
    __syncthreads();
    sm.p2.sred[tid] = ps2;
    __syncthreads();
    for (int s = 128; s > 0; s >>= 1) {
        if (tid < s) sm.p2.sred[tid] += sm.p2.sred[tid + s];
        __syncthreads();
    }
    if (tid == 0) {
        const float psi_sum = sm.p2.sred[0];
        const float rsum = ws[WS_RSUM + 0] + ws[WS_RSUM + 1] + ws[WS_RSUM + 2] + ws[WS_RSUM + 3];
        float loss = 0.f;
        float sacc = 0.f;
        for (int qq = 0; qq < 7; ++qq) { float d = ws[QZF + qq] - ws[QZR + qq]; sacc += d * d; }
        loss += sacc / 7.f;
        loss += (0.5f * s_feas) / ((float)N_PTS * rsum);
        float g = 0.f;
        for (int b = 0; b < B_SZ; ++b) {
            float p = fouts[b];
            g += 0.9f * fmaxf(logf(p), -100.f) + 0.1f * fmaxf(logf(1.f - p), -100.f);
        }
        loss += -g / (float)B_SZ;
        float sx = 0.f, sy = 0.f;
        for (int qq = 0; qq < 5; ++qq) {
            float dx = ws[QXF + qq] - ws[QXR + qq]; sx += dx * dx;
            float dy = ws[QYF + qq] - ws[QYR + qq]; sy += dy * dy;
        }
        loss += 0.5f * (sx / 5.f + sy / 5.f);
        float sd = 0.f;
        for (int t = 0; t < 12; ++t) { float d = ws[QDF + t] - ws[QDR + t]; sd += d * d; }
        loss += sd / 12.f;
        loss += -psi_sum / (float)(B_SZ * N_PTS);
        out[0] = loss;
    }
}

// ---------------- single fused kernel ----------------
// blocks 0..5      : component-array histogram quantiles (independent of pair work)
// blocks 6..1029   : fake clouds — knn + feasibility + hexatic (2 pts/wave)
// blocks 1030..1541: real clouds — knn only (4 pts/wave)
// last-of-cloud block (per-cloud ticket) computes that cloud's knn quantiles;
// last ticket-2 holder (6 comp + 8 cloud-last = 14) does the final combine.
__global__ __launch_bounds__(256) void hs_fused_kernel(const float* __restrict__ real,
                                                       const float* __restrict__ fake,
                                                       const float* __restrict__ fouts,
                                                       float* __restrict__ ws,
                                                       float* __restrict__ out) {
    __shared__ SmemU sm;
    __shared__ unsigned int s_ticket;
    unsigned int* wsu = (unsigned int*)ws;
    const int tid = threadIdx.x, wave = tid >> 6, lane = tid & 63;
    const int blk = blockIdx.x;
    if (blk == 0 && tid < 9) wsu[WS_TICKC + tid] = 0u;   // 8 cloud tickets + ticket2

    if (blk < 6) {
        // ---------- component histogram quantiles ----------
        const int aid = blk;
        const float* src = ((aid & 1) ? real : fake) + ((aid < 2) ? 2 : ((aid < 4) ? 0 : 1));
        const int nq = (aid < 2) ? 7 : 5;
        const int slot = (aid < 2) ? (QZF + aid * 7) : (QXF + (aid - 2) * 5);
        const float* qs = (aid < 2) ? c_qs7 : c_qs5;
        quant_hist(sm, src, 3, 8192, 8.0f, COMP_SCALE, qs, nq,
                   -8.0f, 1.0f / COMP_SCALE, ws, slot, tid, wave, lane);
    } else if (blk < 1030) {
        // ---------- fake fused path (2 targets/wave) ----------
        const int fb = blk - 6;
        const int b = fb >> 8, grp = fb & 255;
        const float* src = fake + (size_t)b * N_PTS * 3;
        for (int t = tid; t < N_PTS; t += 256) {
            const float* p = src + t * 3;
            sm.p1.sxy[t] = make_float2(p[0], p[1]);
            sm.p1.sr[t]  = fabsf(p[2]);
        }
        __syncthreads();
        const int p0 = grp * 8 + wave * 2;
        float px[2], py[2], pri[2], m[2][5];
#pragma unroll
        for (int t = 0; t < 2; ++t) {
            px[t] = sm.p1.sxy[p0 + t].x; py[t] = sm.p1.sxy[p0 + t].y;
            pri[t] = sm.p1.sr[p0 + t] - 1e-4f;
            m[t][0] = m[t][1] = m[t][2] = m[t][3] = m[t][4] = INFINITY;
        }
        // pass 1: squared-dist top-5 (incl self sq=0) + feasibility overlap
        float acc = 0.f;
        for (int j = lane; j < N_PTS; j += 64) {
            float2 q = sm.p1.sxy[j]; float br = sm.p1.sr[j];
#pragma unroll
            for (int t = 0; t < 2; ++t) {
                float dx = px[t] - q.x, dy = py[t] - q.y;
                float sq = fmaf(dx, dx, dy * dy);
                ins5a(m[t], sq);
                float ov = fmaxf((pri[t] + br) - sqrtf(sq), 0.f);
                acc += (sq > 0.f) ? ov : 0.f;
            }
        }
#pragma unroll
        for (int off = 1; off < 64; off <<= 1) {
#pragma unroll
            for (int t = 0; t < 2; ++t) {
                float b0 = __shfl_xor(m[t][0], off);
                float b1 = __shfl_xor(m[t][1], off);
                float b2 = __shfl_xor(m[t][2], off);
                float b3 = __shfl_xor(m[t][3], off);
                float b4 = __shfl_xor(m[t][4], off);
                float l0 = fminf(m[t][0], b4);
                float l1 = fminf(m[t][1], b3);
                float l2 = fminf(m[t][2], b2);
                float l3 = fminf(m[t][3], b1);
                float l4 = fminf(m[t][4], b0);
                CE(l0, l3); CE(l1, l4); CE(l0, l2); CE(l1, l3);
                CE(l0, l1); CE(l2, l4); CE(l1, l2); CE(l3, l4); CE(l2, l3);
                m[t][0] = l0; m[t][1] = l1; m[t][2] = l2; m[t][3] = l3; m[t][4] = l4;
            }
        }
        if (lane == 0) {
            float* kout = ws + WS_KNN_F + b * (N_PTS * 3);
#pragma unroll
            for (int t = 0; t < 2; ++t) {
                const int i = p0 + t;
                kout[i * 3 + 0] = sqrtf(m[t][0] + EPSF);
                kout[i * 3 + 1] = sqrtf(m[t][1] + EPSF);
                kout[i * 3 + 2] = sqrtf(m[t][2] + EPSF);
            }
        }
        float kth[2], invs[2], T2[2];
#pragma unroll
        for (int t = 0; t < 2; ++t) {
            kth[t] = sqrtf(m[t][4] + EPSF);
            const float sigma = fmaxf(0.1f * fmaxf(kth[t], EPSF), EPSF);
            invs[t] = 1.f / sigma;
            const float T = kth[t] + 50.f * sigma;   // arg > -50 iff dist < T
            T2[t] = T * T;
        }
        // pass 2a: lean candidate scan with wave-aggregated compaction
        unsigned int cnt[2] = {0u, 0u};
        const int lbase = wave * 2 * CAP;
        for (int it = 0; it < 32; ++it) {
            const int j = it * 64 + lane;
            float2 q = sm.p1.sxy[j];
#pragma unroll
            for (int t = 0; t < 2; ++t) {
                float dx = px[t] - q.x, dy = py[t] - q.y;
                float sq = fmaf(dx, dx, dy * dy);
                const bool p = (sq <= T2[t]);
                const unsigned long long mk = __ballot(p);
                const unsigned int below = __builtin_amdgcn_mbcnt_hi(
                    (unsigned int)(mk >> 32),
                    __builtin_amdgcn_mbcnt_lo((unsigned int)mk, 0u));
                const unsigned int off = cnt[t] + below;
                if (p && off < CAP) sm.p1.slist[lbase + t * CAP + off] = (unsigned short)j;
                cnt[t] += (unsigned int)__popcll((long long)mk);
            }
        }
        // pass 2b: weighted e^{i4theta} over candidates (fallback: all pairs)
        float mypsi = 0.f;
#pragma unroll
        for (int t = 0; t < 2; ++t) {
            float swv = 0.f, srev = 0.f, simv = 0.f;
            if (cnt[t] <= CAP) {
                const int len = (int)cnt[t];
                for (int i = lane; i < len; i += 64) {
                    const int j = sm.p1.slist[lbase + t * CAP + i];
                    float2 q = sm.p1.sxy[j];
                    float dx = px[t] - q.x, dy = py[t] - q.y;
                    float sq = fmaf(dx, dx, dy * dy);
                    float dist = sqrtf(sq + EPSF);
                    dist = (j == p0 + t) ? INFINITY : dist;
                    float a = dx + ((fabsf(dx) < EPSF) ? EPSF : 0.f);
                    float arg = fminf(fmaxf((kth[t] - dist) * invs[t], -50.f), 50.f);
                    float e = __expf(-arg);
                    float w = __builtin_amdgcn_rcpf(1.f + e);
                    float aa = a * a, bb = dy * dy;
                    float n2 = aa + bb;
                    float z2r = aa - bb;
                    float t0 = a * dy; float z2i = t0 + t0;
                    float inv = __builtin_amdgcn_rcpf(n2);
                    float ur = z2r * inv, ui = z2i * inv;
                    float e4r = fmaf(ur, ur, -(ui * ui));
                    float t1 = ur * ui; float e4i = t1 + t1;
                    swv += w;
                    srev = fmaf(w, e4r, srev);
                    simv = fmaf(w, e4i, simv);
                }
            } else {
                for (int j = lane; j < N_PTS; j += 64) {
                    float2 q = sm.p1.sxy[j];
                    float dx = px[t] - q.x, dy = py[t] - q.y;
                    float sq = fmaf(dx, dx, dy * dy);
                    float dist = sqrtf(sq + EPSF);
                    dist = (j == p0 + t) ? INFINITY : dist;
                    float a = dx + ((fabsf(dx) < EPSF) ? EPSF : 0.f);
                    float arg = fminf(fmaxf((kth[t] - dist) * invs[t], -50.f), 50.f);
                    float e = __expf(-arg);
                    float w = __builtin_amdgcn_rcpf(1.f + e);
                    float aa = a * a, bb = dy * dy;
                    float n2 = aa + bb;
                    float z2r = aa - bb;
                    float t0 = a * dy; float z2i = t0 + t0;
                    float inv = __builtin_amdgcn_rcpf(n2);
                    float ur = z2r * inv, ui = z2i * inv;
                    float e4r = fmaf(ur, ur, -(ui * ui));
                    float t1 = ur * ui; float e4i = t1 + t1;
                    swv += w;
                    srev = fmaf(w, e4r, srev);
                    simv = fmaf(w, e4i, simv);
                }
            }
#pragma unroll
            for (int off = 1; off < 64; off <<= 1) {
                swv  += __shfl_xor(swv, off);
                srev += __shfl_xor(srev, off);
                simv += __shfl_xor(simv, off);
            }
            if (lane == 0) {
                const float den = fmaxf(swv, EPSF);
                const float pr = srev / den, pi = simv / den;
                mypsi += sqrtf(fmaf(pr, pr, pi * pi));
            }
        }
        sm.p1.red[tid] = acc;
        __syncthreads();
        for (int s = 128; s > 0; s >>= 1) {
            if (tid < s) sm.p1.red[tid] += sm.p1.red[tid + s];
            __syncthreads();
        }
        if (tid == 0) ws[WS_FEAS + fb] = sm.p1.red[0];
        __syncthreads();
        sm.p1.red[tid] = (lane == 0) ? mypsi : 0.f;
        __syncthreads();
        for (int s = 128; s > 0; s >>= 1) {
            if (tid < s) sm.p1.red[tid] += sm.p1.red[tid + s];
            __syncthreads();
        }
        if (tid == 0) ws[WS_PSIP + fb] = sm.p1.red[0];
        if (grp == 0) {
            __syncthreads();
            float rs = 0.f;
            for (int t = tid; t < N_PTS; t += 256) rs += sm.p1.sr[t];
            sm.p1.red[tid] = rs;
            __syncthreads();
            for (int s = 128; s > 0; s >>= 1) {
                if (tid < s) sm.p1.red[tid] += sm.p1.red[tid + s];
                __syncthreads();
            }
            if (tid == 0) ws[WS_RSUM + b] = sm.p1.red[0];
        }
        // ---- per-cloud ticket: last fake block of cloud b does its knn quantiles ----
        __threadfence();
        __syncthreads();
        if (tid == 0) s_ticket = atomicAdd(&wsu[WS_TICKC + b], 1u);
        __syncthreads();
        if (s_ticket != 255u) return;
        __threadfence();
        quant_hist(sm, ws + WS_KNN_F + b * (N_PTS * 3), 1, N_PTS * 3, 0.0f, KNN_SCALE,
                   c_qs3, 3, 0.0f, 1.0f / KNN_SCALE, ws, QDF + b * 3, tid, wave, lane);
    } else {
        // ---------- real knn path (4 targets/wave) ----------
        const int rb = blk - 1030;
        const int b = rb >> 7, grp = rb & 127;
        const float* src = real + (size_t)b * N_PTS * 3;
        for (int t = tid; t < N_PTS; t += 256) {
            const float* p = src + t * 3;
            sm.p1.sxy[t] = make_float2(p[0], p[1]);
        }
        __syncthreads();
        const int p0 = grp * 16 + wave * 4;
        float px[4], py[4], m[4][3];
#pragma unroll
        for (int t = 0; t < 4; ++t) {
            px[t] = sm.p1.sxy[p0 + t].x; py[t] = sm.p1.sxy[p0 + t].y;
            m[t][0] = m[t][1] = m[t][2] = INFINITY;
        }
        for (int j = lane; j < N_PTS; j += 64) {
            float2 q = sm.p1.sxy[j];
#pragma unroll
            for (int t = 0; t < 4; ++t) {
                float dx = px[t] - q.x, dy = py[t] - q.y;
                float sq = fmaf(dx, dx, dy * dy);
                ins3a(m[t], sq);
            }
        }
#pragma unroll
        for (int off = 1; off < 64; off <<= 1) {
#pragma unroll
            for (int t = 0; t < 4; ++t) {
                float b0 = __shfl_xor(m[t][0], off);
                float b1 = __shfl_xor(m[t][1], off);
                float b2 = __shfl_xor(m[t][2], off);
                float l0 = fminf(m[t][0], b2);
                float l1 = fminf(m[t][1], b1);
                float l2 = fminf(m[t][2], b0);
                CE(l0, l1); CE(l0, l2); CE(l1, l2);
                m[t][0] = l0; m[t][1] = l1; m[t][2] = l2;
            }
        }
        if (lane == 0) {
            float* kout = ws + WS_KNN_R + b * (N_PTS * 3);
#pragma unroll
            for (int t = 0; t < 4; ++t) {
                const int i = p0 + t;
                kout[i * 3 + 0] = sqrtf(m[t][0] + EPSF);
                kout[i * 3 + 1] = sqrtf(m[t][1] + EPSF);
                kout[i * 3 + 2] = sqrtf(m[t][2] + EPSF);
            }
        }
        // ---- per-cloud ticket: last real block of cloud b does its knn quantiles ----
        __threadfence();
        __syncthreads();
        if (tid == 0) s_ticket = atomicAdd(&wsu[WS_TICKC + 4 + b], 1u);
        __syncthreads();
        if (s_ticket != 127u) return;
        __threadfence();
        quant_hist(sm, ws + WS_KNN_R + b * (N_PTS * 3), 1, N_PTS * 3, 0.0f, KNN_SCALE,
                   c_qs3, 3, 0.0f, 1.0f / KNN_SCALE, ws, QDR + b * 3, tid, wave, lane);
    }

    // ---- ticket 2 (6 comp + 8 cloud-last = 14): last holder runs the final combine ----
    __threadfence();
    __syncthreads();
    if (tid == 0) {
        const unsigned int t2 = atomicAdd(&wsu[WS_TICK2], 1u);
        sm.p2.slast = (t2 == 13u) ? 1 : 0;
    }
    __syncthreads();
    if (!sm.p2.slast) return;
    __threadfence();
    final_combine(sm, fouts, ws, out, tid);
}

extern "C" void kernel_launch(void* const* d_in, const int* in_sizes, int n_in,
                              void* d_out, int out_size, void* d_ws, size_t ws_size,
                              hipStream_t stream) {
    (void)in_sizes; (void)n_in; (void)out_size; (void)ws_size;
    const float* real  = (const float*)d_in[0];
    const float* fake  = (const float*)d_in[1];
    const float* fouts = (const float*)d_in[2];
    float* out = (float*)d_out;
    float* ws  = (float*)d_ws;

    hipLaunchKernelGGL(hs_fused_kernel, dim3(1542), dim3(256), 0, stream, real, fake, fouts, ws, out);
}

// Round 12
// 111.452 us; speedup vs baseline: 1.7726x; 1.7726x over previous
//
#include <hip/hip_runtime.h>
#include <math.h>

#define B_SZ   4
#define N_PTS  2048
#define EPSF   1e-6f
#define CAP    500     // candidate-list capacity per (wave,target); LDS budget <=32KB

// ---- workspace float-index layout ----
#define WS_KNN_R 0                       // 4*6144 real knn dists
#define WS_KNN_F 24576                   // 4*6144 fake knn dists
#define WS_FEAS  49152                   // 1024 feasibility partials
#define WS_PSIP  50176                   // 1024 psi partials
#define WS_RSUM  51200                   // 4 per-batch sum|r|
#define WS_Q     51204                   // 58 quantile outputs
#define WS_TICK  51264                   // uint ticket (zeroed by pair blk 0)
#define QZF (WS_Q + 0)
#define QZR (WS_Q + 7)
#define QXF (WS_Q + 14)
#define QXR (WS_Q + 19)
#define QYF (WS_Q + 24)
#define QYR (WS_Q + 29)
#define QDR (WS_Q + 34)   // 4 batches x 3 (real knn)
#define QDF (WS_Q + 46)   // 4 batches x 3 (fake knn)
#define COMP_SCALE 256.0f     // component bins over [-8,8), width 1/256
#define KNN_SCALE  1024.0f    // knn bins over [0,4), width 1/1024

__constant__ float c_qs7[7] = {0.05f, 0.1f, 0.25f, 0.5f, 0.75f, 0.9f, 0.95f};
__constant__ float c_qs5[5] = {0.05f, 0.25f, 0.5f, 0.75f, 0.95f};
__constant__ float c_qs3[3] = {0.05f, 0.5f, 0.95f};

#define CE(a, b) { float _lo = fminf(a, b), _hi = fmaxf(a, b); a = _lo; b = _hi; }

__device__ __forceinline__ void ins3a(float m[3], float v) {
    float h0 = fmaxf(m[0], v); m[0] = fminf(m[0], v);
    float h1 = fmaxf(m[1], h0); m[1] = fminf(m[1], h0);
    m[2] = fminf(m[2], h1);
}
__device__ __forceinline__ void ins5a(float m[5], float v) {
    float h0 = fmaxf(m[0], v); m[0] = fminf(m[0], v);
    float h1 = fmaxf(m[1], h0); m[1] = fminf(m[1], h0);
    float h2 = fmaxf(m[2], h1); m[2] = fminf(m[2], h1);
    float h3 = fmaxf(m[3], h2); m[3] = fminf(m[3], h2);
    m[4] = fminf(m[4], h3);
}

// ---------------- kernel A: pair work ----------------
// blocks 0..1023   : fake clouds — knn + feasibility + hexatic (2 pts/wave)
// blocks 1024..1535: real clouds — knn only (4 pts/wave)
// LDS kept under 32 KB -> 5 blocks/CU (vs 4 at R10's 37.9 KB).
__global__ __launch_bounds__(256) void hs_pair_kernel(const float* __restrict__ real,
                                                      const float* __restrict__ fake,
                                                      float* __restrict__ ws) {
    __shared__ float2 sxy[N_PTS];                    // 16 KB
    __shared__ float sr[N_PTS];                      // 8 KB
    __shared__ unsigned short slist[4 * 2 * CAP];    // 8 KB candidate lists
    __shared__ float s4[4];                          // cross-wave scratch
    const int tid = threadIdx.x, wave = tid >> 6, lane = tid & 63;
    const int blk = blockIdx.x;
    if (blk == 0 && tid == 0) ((unsigned int*)ws)[WS_TICK] = 0u;

    if (blk < 1024) {
        // ---------- fake fused path (2 targets/wave) ----------
        const int b = blk >> 8, grp = blk & 255;
        const float* src = fake + (size_t)b * N_PTS * 3;
        for (int t = tid; t < N_PTS; t += 256) {
            const float* p = src + t * 3;
            sxy[t] = make_float2(p[0], p[1]);
            sr[t]  = fabsf(p[2]);
        }
        __syncthreads();
        const int p0 = grp * 8 + wave * 2;
        float px[2], py[2], pri[2], m[2][5];
#pragma unroll
        for (int t = 0; t < 2; ++t) {
            px[t] = sxy[p0 + t].x; py[t] = sxy[p0 + t].y;
            pri[t] = sr[p0 + t] - 1e-4f;
            m[t][0] = m[t][1] = m[t][2] = m[t][3] = m[t][4] = INFINITY;
        }
        // pass 1: squared-dist top-5 (incl self sq=0) + feasibility overlap
        float acc = 0.f;
        for (int j = lane; j < N_PTS; j += 64) {
            float2 q = sxy[j]; float br = sr[j];
#pragma unroll
            for (int t = 0; t < 2; ++t) {
                float dx = px[t] - q.x, dy = py[t] - q.y;
                float sq = fmaf(dx, dx, dy * dy);
                ins5a(m[t], sq);
                float ov = fmaxf((pri[t] + br) - sqrtf(sq), 0.f);
                acc += (sq > 0.f) ? ov : 0.f;
            }
        }
#pragma unroll
        for (int off = 1; off < 64; off <<= 1) {
#pragma unroll
            for (int t = 0; t < 2; ++t) {
                float b0 = __shfl_xor(m[t][0], off);
                float b1 = __shfl_xor(m[t][1], off);
                float b2 = __shfl_xor(m[t][2], off);
                float b3 = __shfl_xor(m[t][3], off);
                float b4 = __shfl_xor(m[t][4], off);
                float l0 = fminf(m[t][0], b4);
                float l1 = fminf(m[t][1], b3);
                float l2 = fminf(m[t][2], b2);
                float l3 = fminf(m[t][3], b1);
                float l4 = fminf(m[t][4], b0);
                CE(l0, l3); CE(l1, l4); CE(l0, l2); CE(l1, l3);
                CE(l0, l1); CE(l2, l4); CE(l1, l2); CE(l3, l4); CE(l2, l3);
                m[t][0] = l0; m[t][1] = l1; m[t][2] = l2; m[t][3] = l3; m[t][4] = l4;
            }
        }
        if (lane == 0) {
            float* kout = ws + WS_KNN_F + b * (N_PTS * 3);
#pragma unroll
            for (int t = 0; t < 2; ++t) {
                const int i = p0 + t;
                kout[i * 3 + 0] = sqrtf(m[t][0] + EPSF);
                kout[i * 3 + 1] = sqrtf(m[t][1] + EPSF);
                kout[i * 3 + 2] = sqrtf(m[t][2] + EPSF);
            }
        }
        float kth[2], invs[2], T2[2];
#pragma unroll
        for (int t = 0; t < 2; ++t) {
            kth[t] = sqrtf(m[t][4] + EPSF);
            const float sigma = fmaxf(0.1f * fmaxf(kth[t], EPSF), EPSF);
            invs[t] = 1.f / sigma;
            const float T = kth[t] + 50.f * sigma;   // arg > -50 iff dist < T
            T2[t] = T * T;
        }
        // pass 2a: lean candidate scan with wave-aggregated compaction.
        // sq > T^2 -> arg clamps to -50 -> w ~1.9e-22: dropping perturbs sums <4e-19.
        unsigned int cnt[2] = {0u, 0u};
        const int lbase = wave * 2 * CAP;
        for (int it = 0; it < 32; ++it) {
            const int j = it * 64 + lane;
            float2 q = sxy[j];
#pragma unroll
            for (int t = 0; t < 2; ++t) {
                float dx = px[t] - q.x, dy = py[t] - q.y;
                float sq = fmaf(dx, dx, dy * dy);
                const bool p = (sq <= T2[t]);
                const unsigned long long mk = __ballot(p);
                const unsigned int below = __builtin_amdgcn_mbcnt_hi(
                    (unsigned int)(mk >> 32),
                    __builtin_amdgcn_mbcnt_lo((unsigned int)mk, 0u));
                const unsigned int off = cnt[t] + below;
                if (p && off < CAP) slist[lbase + t * CAP + off] = (unsigned short)j;
                cnt[t] += (unsigned int)__popcll((long long)mk);
            }
        }
        // pass 2b: full weighted e^{i4theta} over candidates (fallback: all pairs)
        float mypsi = 0.f;
#pragma unroll
        for (int t = 0; t < 2; ++t) {
            float swv = 0.f, srev = 0.f, simv = 0.f;
            if (cnt[t] <= CAP) {
                const int len = (int)cnt[t];
                for (int i = lane; i < len; i += 64) {
                    const int j = slist[lbase + t * CAP + i];
                    float2 q = sxy[j];
                    float dx = px[t] - q.x, dy = py[t] - q.y;
                    float sq = fmaf(dx, dx, dy * dy);
                    float dist = sqrtf(sq + EPSF);
                    dist = (j == p0 + t) ? INFINITY : dist;
                    float a = dx + ((fabsf(dx) < EPSF) ? EPSF : 0.f);
                    float arg = fminf(fmaxf((kth[t] - dist) * invs[t], -50.f), 50.f);
                    float e = __expf(-arg);
                    float w = __builtin_amdgcn_rcpf(1.f + e);
                    float aa = a * a, bb = dy * dy;
                    float n2 = aa + bb;
                    float z2r = aa - bb;
                    float t0 = a * dy; float z2i = t0 + t0;
                    float inv = __builtin_amdgcn_rcpf(n2);
                    float ur = z2r * inv, ui = z2i * inv;
                    float e4r = fmaf(ur, ur, -(ui * ui));
                    float t1 = ur * ui; float e4i = t1 + t1;
                    swv += w;
                    srev = fmaf(w, e4r, srev);
                    simv = fmaf(w, e4i, simv);
                }
            } else {
                for (int j = lane; j < N_PTS; j += 64) {
                    float2 q = sxy[j];
                    float dx = px[t] - q.x, dy = py[t] - q.y;
                    float sq = fmaf(dx, dx, dy * dy);
                    float dist = sqrtf(sq + EPSF);
                    dist = (j == p0 + t) ? INFINITY : dist;
                    float a = dx + ((fabsf(dx) < EPSF) ? EPSF : 0.f);
                    float arg = fminf(fmaxf((kth[t] - dist) * invs[t], -50.f), 50.f);
                    float e = __expf(-arg);
                    float w = __builtin_amdgcn_rcpf(1.f + e);
                    float aa = a * a, bb = dy * dy;
                    float n2 = aa + bb;
                    float z2r = aa - bb;
                    float t0 = a * dy; float z2i = t0 + t0;
                    float inv = __builtin_amdgcn_rcpf(n2);
                    float ur = z2r * inv, ui = z2i * inv;
                    float e4r = fmaf(ur, ur, -(ui * ui));
                    float t1 = ur * ui; float e4i = t1 + t1;
                    swv += w;
                    srev = fmaf(w, e4r, srev);
                    simv = fmaf(w, e4i, simv);
                }
            }
#pragma unroll
            for (int off = 1; off < 64; off <<= 1) {
                swv  += __shfl_xor(swv, off);
                srev += __shfl_xor(srev, off);
                simv += __shfl_xor(simv, off);
            }
            if (lane == 0) {
                const float den = fmaxf(swv, EPSF);
                const float pr = srev / den, pi = simv / den;
                mypsi += sqrtf(fmaf(pr, pr, pi * pi));
            }
        }
        // block reductions via wave shfl + 4-float scratch
        float accw = acc;
#pragma unroll
        for (int off = 1; off < 64; off <<= 1) accw += __shfl_xor(accw, off);
        if (lane == 0) s4[wave] = accw;
        __syncthreads();
        if (tid == 0) ws[WS_FEAS + blk] = s4[0] + s4[1] + s4[2] + s4[3];
        __syncthreads();
        if (lane == 0) s4[wave] = mypsi;
        __syncthreads();
        if (tid == 0) ws[WS_PSIP + blk] = s4[0] + s4[1] + s4[2] + s4[3];
        if (grp == 0) {
            float rs = 0.f;
            for (int t = tid; t < N_PTS; t += 256) rs += sr[t];
#pragma unroll
            for (int off = 1; off < 64; off <<= 1) rs += __shfl_xor(rs, off);
            __syncthreads();
            if (lane == 0) s4[wave] = rs;
            __syncthreads();
            if (tid == 0) ws[WS_RSUM + b] = s4[0] + s4[1] + s4[2] + s4[3];
        }
    } else {
        // ---------- real knn path (4 targets/wave) ----------
        const int rb = blk - 1024;
        const int b = rb >> 7, grp = rb & 127;
        const float* src = real + (size_t)b * N_PTS * 3;
        for (int t = tid; t < N_PTS; t += 256) {
            const float* p = src + t * 3;
            sxy[t] = make_float2(p[0], p[1]);
        }
        __syncthreads();
        const int p0 = grp * 16 + wave * 4;
        float px[4], py[4], m[4][3];
#pragma unroll
        for (int t = 0; t < 4; ++t) {
            px[t] = sxy[p0 + t].x; py[t] = sxy[p0 + t].y;
            m[t][0] = m[t][1] = m[t][2] = INFINITY;
        }
        for (int j = lane; j < N_PTS; j += 64) {
            float2 q = sxy[j];
#pragma unroll
            for (int t = 0; t < 4; ++t) {
                float dx = px[t] - q.x, dy = py[t] - q.y;
                float sq = fmaf(dx, dx, dy * dy);
                ins3a(m[t], sq);
            }
        }
#pragma unroll
        for (int off = 1; off < 64; off <<= 1) {
#pragma unroll
            for (int t = 0; t < 4; ++t) {
                float b0 = __shfl_xor(m[t][0], off);
                float b1 = __shfl_xor(m[t][1], off);
                float b2 = __shfl_xor(m[t][2], off);
                float l0 = fminf(m[t][0], b2);
                float l1 = fminf(m[t][1], b1);
                float l2 = fminf(m[t][2], b0);
                CE(l0, l1); CE(l0, l2); CE(l1, l2);
                m[t][0] = l0; m[t][1] = l1; m[t][2] = l2;
            }
        }
        if (lane == 0) {
            float* kout = ws + WS_KNN_R + b * (N_PTS * 3);
#pragma unroll
            for (int t = 0; t < 4; ++t) {
                const int i = p0 + t;
                kout[i * 3 + 0] = sqrtf(m[t][0] + EPSF);
                kout[i * 3 + 1] = sqrtf(m[t][1] + EPSF);
                kout[i * 3 + 2] = sqrtf(m[t][2] + EPSF);
            }
        }
    }
}

// ---------------- kernel B: LDS histogram quantiles + fused final ----------------
// 14 blocks x 256 (4 waves). Block per array: build 4096-bin LDS histogram with
// per-wave replicas, block scan, interpolate quantiles. Last-ticket block -> final.
__global__ __launch_bounds__(256) void hs_quant_kernel(const float* __restrict__ real,
                                                       const float* __restrict__ fake,
                                                       const float* __restrict__ fouts,
                                                       float* __restrict__ ws,
                                                       float* __restrict__ out) {
    __shared__ unsigned int hist[4][4096];   // 64 KB; hist[0] reused as cum
    __shared__ unsigned int s_wsum[4];
    __shared__ float sred[256];
    __shared__ int s_last;
    unsigned int* wsu = (unsigned int*)ws;
    const int tid = threadIdx.x, wave = tid >> 6, lane = tid & 63;
    const int aid = blockIdx.x;

    const float* src; int step, n, nq, slot; float vlo, vw; const float* qs;
    if (aid < 6) {
        src = ((aid & 1) ? real : fake) + ((aid < 2) ? 2 : ((aid < 4) ? 0 : 1));
        step = 3; n = 8192;
        nq = (aid < 2) ? 7 : 5;
        slot = (aid < 2) ? (QZF + aid * 7) : (QXF + (aid - 2) * 5);
        vlo = -8.f; vw = 1.f / COMP_SCALE;
        qs = (aid < 2) ? c_qs7 : c_qs5;
    } else {
        const int a = aid - 6;   // 0..3 real, 4..7 fake
        src = ws + ((a < 4) ? WS_KNN_R + a * (N_PTS * 3) : WS_KNN_F + (a - 4) * (N_PTS * 3));
        step = 1; n = N_PTS * 3; nq = 3;
        slot = (a < 4) ? (QDR + a * 3) : (QDF + (a - 4) * 3);
        vlo = 0.f; vw = 1.f / KNN_SCALE;
        qs = c_qs3;
    }

    unsigned int* hflat = &hist[0][0];
#pragma unroll
    for (int i = 0; i < 64; ++i) hflat[i * 256 + tid] = 0u;
    __syncthreads();

    const float scale = (aid < 6) ? COMP_SCALE : KNN_SCALE;
    const float bias  = (aid < 6) ? 8.0f : 0.0f;
    for (int e = tid; e < n; e += 256) {
        const float v = src[(size_t)e * step];
        int bin = (int)floorf((v + bias) * scale);
        bin = (bin < 0) ? 0 : (bin > 4095 ? 4095 : bin);
        atomicAdd(&hist[wave][bin], 1u);
    }
    __syncthreads();

    unsigned int c[16], ps = 0;
    const int base = tid * 16;
#pragma unroll
    for (int i = 0; i < 16; ++i) {
        c[i] = hist[0][base + i] + hist[1][base + i] + hist[2][base + i] + hist[3][base + i];
        ps += c[i];
    }
    unsigned int incl = ps;
#pragma unroll
    for (int off = 1; off < 64; off <<= 1) {
        unsigned int nb = (unsigned int)__shfl_up((int)incl, off);
        if (lane >= off) incl += nb;
    }
    if (lane == 63) s_wsum[wave] = incl;
    __syncthreads();
    unsigned int woff = 0;
    for (int w2 = 0; w2 < wave; ++w2) woff += s_wsum[w2];
    unsigned int run = incl - ps + woff;
    unsigned int* sh_cum = &hist[0][0];
#pragma unroll
    for (int i = 0; i < 16; ++i) { run += c[i]; sh_cum[base + i] = run; }
    __syncthreads();

    if (tid < nq) {
        const float pos = qs[tid] * (float)(n - 1);
        const int k = (int)pos;
        const float frac = pos - (float)k;
        float v2[2];
#pragma unroll
        for (int t = 0; t < 2; ++t) {
            const unsigned int r = (unsigned int)(k + t);
            int lo_ = 0, hi_ = 4095;
            while (lo_ < hi_) {
                const int mid = (lo_ + hi_) >> 1;
                if (sh_cum[mid] > r) hi_ = mid; else lo_ = mid + 1;
            }
            const unsigned int excl = (lo_ > 0) ? sh_cum[lo_ - 1] : 0u;
            const unsigned int cnt  = sh_cum[lo_] - excl;
            v2[t] = vlo + ((float)lo_ + ((float)(r - excl) + 0.5f) / (float)cnt) * vw;
        }
        ws[slot + tid] = v2[0] + frac * (v2[1] - v2[0]);
    }

    __threadfence();
    __syncthreads();
    if (tid == 0) {
        const unsigned int t = atomicAdd(&wsu[WS_TICK], 1u);
        s_last = (t == 13u) ? 1 : 0;
    }
    __syncthreads();
    if (!s_last) return;
    __threadfence();

    float fs = 0.f, ps2 = 0.f;
    for (int t = tid; t < 1024; t += 256) {
        fs  += ws[WS_FEAS + t];
        ps2 += ws[WS_PSIP + t];
    }
    sred[tid] = fs;
    __syncthreads();
    for (int s = 128; s > 0; s >>= 1) {
        if (tid < s) sred[tid] += sred[tid + s];
        __syncthreads();
    }
    const float s_feas = sred[0];
    __syncthreads();
    sred[tid] = ps2;
    __syncthreads();
    for (int s = 128; s > 0; s >>= 1) {
        if (tid < s) sred[tid] += sred[tid + s];
        __syncthreads();
    }
    if (tid == 0) {
        const float psi_sum = sred[0];
        const float rsum = ws[WS_RSUM + 0] + ws[WS_RSUM + 1] + ws[WS_RSUM + 2] + ws[WS_RSUM + 3];
        float loss = 0.f;
        float sacc = 0.f;
        for (int qq = 0; qq < 7; ++qq) { float d = ws[QZF + qq] - ws[QZR + qq]; sacc += d * d; }
        loss += sacc / 7.f;
        loss += (0.5f * s_feas) / ((float)N_PTS * rsum);
        float g = 0.f;
        for (int b = 0; b < B_SZ; ++b) {
            float p = fouts[b];
            g += 0.9f * fmaxf(logf(p), -100.f) + 0.1f * fmaxf(logf(1.f - p), -100.f);
        }
        loss += -g / (float)B_SZ;
        float sx = 0.f, sy = 0.f;
        for (int qq = 0; qq < 5; ++qq) {
            float dx = ws[QXF + qq] - ws[QXR + qq]; sx += dx * dx;
            float dy = ws[QYF + qq] - ws[QYR + qq]; sy += dy * dy;
        }
        loss += 0.5f * (sx / 5.f + sy / 5.f);
        float sd = 0.f;
        for (int t = 0; t < 12; ++t) { float d = ws[QDF + t] - ws[QDR + t]; sd += d * d; }
        loss += sd / 12.f;
        loss += -psi_sum / (float)(B_SZ * N_PTS);
        out[0] = loss;
    }
}

extern "C" void kernel_launch(void* const* d_in, const int* in_sizes, int n_in,
                              void* d_out, int out_size, void* d_ws, size_t ws_size,
                              hipStream_t stream) {
    (void)in_sizes; (void)n_in; (void)out_size; (void)ws_size;
    const float* real  = (const float*)d_in[0];
    const float* fake  = (const float*)d_in[1];
    const float* fouts = (const float*)d_in[2];
    float* out = (float*)d_out;
    float* ws  = (float*)d_ws;

    hipLaunchKernelGGL(hs_pair_kernel,  dim3(1536), dim3(256), 0, stream, real, fake, ws);
    hipLaunchKernelGGL(hs_quant_kernel, dim3(14),   dim3(256), 0, stream, real, fake, fouts, ws, out);
}